// Round 8
// baseline (494.684 us; speedup 1.0000x reference)
//
#include <hip/hip_runtime.h>
#include <math.h>

#define TPC 225
#define NCLS 224
#define NHID 1024
#define BATCH 2048
#define CAP 256      // bucket capacity per class (mean ~9.1)
#define LSTRIDE 256  // logits ws row stride (floats)

// blogits geometry (HBM-streamed weights)
#define NCHUNK 8     // d-chunks per row
#define CHUNK_D 128  // NHID / NCHUNK
#define NDQ 32       // CHUNK_D / 4

// tlogits geometry (LDS-staged weights)
#define TCH 16       // d-chunks
#define TCH_D 64     // d per chunk
#define TROWS 32     // rows per block (8 waves x 4)
#define TPAD 228     // padded LDS row stride (dwords, 228%32=4 -> no bank alias)

// ---------------------------------------------------------------------------
// Kernel 1: bucket examples by class. Single block, LDS atomics.
// ---------------------------------------------------------------------------
__global__ __launch_bounds__(256) void hs_bucket(const int* __restrict__ labels,
                                                 int* __restrict__ bucket,
                                                 int* __restrict__ cnt) {
    __shared__ int scnt[NCLS];
    const int t = threadIdx.x;
    for (int i = t; i < NCLS; i += 256) scnt[i] = 0;
    __syncthreads();
    for (int b = t; b < BATCH; b += 256) {
        int lab = labels[b];
        int c = lab / TPC;
        int pos = atomicAdd(&scnt[c], 1);
        bucket[c * CAP + pos] = b;
    }
    __syncthreads();
    for (int i = t; i < NCLS; i += 256) cnt[i] = scnt[i];
}

// ---------------------------------------------------------------------------
// Kernel 2: top logits, LDS-staged weights. W_top is only 0.9 MB but was
// re-read ~500x through L2 by every CU (same-line bank contention kept three
// different register-level structures all at ~280 us). Now: each block
// stages one 64-d x 224-col tile (57 KB LDS, reg->ds_write, coalesced) ONCE,
// then 8 waves x 4 rows compute from LDS (stride-1 conflict-free b32 reads,
// ~120 cy latency, zero cross-CU contention). Grid = 64 row-tiles x 16
// chunks = 1024 blocks; 16 partial buffers summed in finish.
// ---------------------------------------------------------------------------
__global__ __launch_bounds__(512, 2) void hs_tlogits(const float* __restrict__ x,
                                                     const float* __restrict__ W,
                                                     float* __restrict__ twsP) {
    __shared__ float lw[TCH_D * TPAD];  // 58368 B -> 2 blocks/CU
    const int rb = blockIdx.x >> 4;  // row-tile 0..63
    const int q = blockIdx.x & 15;   // d-chunk 0..15
    const int t = threadIdx.x;
    const int lane = t & 63;
    const int wv = t >> 6;           // wave 0..7

    // stage: wave wv stages rows wv, wv+8, ... (56 lanes x float4 = full row)
    for (int r = wv; r < TCH_D; r += 8) {
        if (lane < 56) {
            float4 v = *(const float4*)(W + (size_t)(q * TCH_D + r) * NCLS + 4 * lane);
            *(float4*)(&lw[r * TPAD + 4 * lane]) = v;
        }
    }
    __syncthreads();

    int rows[4];
#pragma unroll
    for (int rl = 0; rl < 4; rl++) rows[rl] = rb * TROWS + wv * 4 + rl;
    const float* xp[4];
#pragma unroll
    for (int rl = 0; rl < 4; rl++)
        xp[rl] = x + (size_t)rows[rl] * NHID + q * TCH_D;
    int kcl[4];
#pragma unroll
    for (int j = 0; j < 4; j++) {
        int k = lane + 64 * j;
        kcl[j] = (k < NCLS) ? k : (NCLS - 1);
    }

    float acc[4][4] = {};
    for (int dq = 0; dq < TCH_D / 4; ++dq) {  // 16
        float w[4][4];
#pragma unroll
        for (int di = 0; di < 4; di++)
#pragma unroll
            for (int j = 0; j < 4; j++)
                w[di][j] = lw[(dq * 4 + di) * TPAD + kcl[j]];
        float4 xq[4];
#pragma unroll
        for (int rl = 0; rl < 4; rl++)
            xq[rl] = *(const float4*)(xp[rl] + dq * 4);
#pragma unroll
        for (int rl = 0; rl < 4; rl++)
#pragma unroll
            for (int di = 0; di < 4; di++) {
                float xv = ((const float*)&xq[rl])[di];
#pragma unroll
                for (int j = 0; j < 4; j++)
                    acc[rl][j] = fmaf(xv, w[di][j], acc[rl][j]);
            }
    }

    float* tp = twsP + (size_t)q * BATCH * LSTRIDE;
#pragma unroll
    for (int rl = 0; rl < 4; rl++)
#pragma unroll
        for (int j = 0; j < 4; j++) {
            int k = lane + 64 * j;
            if (k < NCLS) tp[(size_t)rows[rl] * LSTRIDE + k] = acc[rl][j];
        }
}

// ---------------------------------------------------------------------------
// Kernel 3: bottom logits — dwordx4 weight loads, SINGLE-buffered (the R6
// double-buffer spilled; acc16+w16+x16 ~= 56 regs fits the 64-VGPR ceiling).
// Lane owns k = 4*lane+j via R6's proven clamp (tail lanes duplicate cols
// 221-224: unaligned-but-working loads, duplicate stores benign). 4x fewer
// VMEM instrs, 4x more bytes per outstanding load in the HBM-latency regime.
// Grid = 224 classes x 8 chunks; 4 waves = 4 row-groups.
// ---------------------------------------------------------------------------
template <int RW>
__device__ __forceinline__ void bchunk(const float* __restrict__ xb,
                                       const float* __restrict__ wq,
                                       const int* __restrict__ bucket_c,
                                       const int base, const int n,
                                       const int lane, const int wr,
                                       float* __restrict__ bp) {
    int rows[RW], rval[RW];
#pragma unroll
    for (int rl = 0; rl < RW; rl++) {
        int idx = base + wr * RW + rl;
        rows[rl] = bucket_c[idx < n ? idx : 0];  // pad rows alias entry 0
        rval[rl] = (idx < n);
    }
    const float* xp[RW];
#pragma unroll
    for (int rl = 0; rl < RW; rl++) xp[rl] = xb + (size_t)rows[rl] * NHID;
    const int kb = (4 * lane <= TPC - 4) ? 4 * lane : (TPC - 4);  // 221 tail
    const float* pw = wq + kb;

    float acc[RW][4] = {};
    for (int dq = 0; dq < NDQ; ++dq) {
        float4 wv4[4];
#pragma unroll
        for (int di = 0; di < 4; di++)
            wv4[di] = *(const float4*)(pw + di * TPC);
        pw += 4 * TPC;
        float4 xq[RW];
#pragma unroll
        for (int rl = 0; rl < RW; rl++)
            xq[rl] = *(const float4*)(xp[rl] + dq * 4);
#pragma unroll
        for (int rl = 0; rl < RW; rl++)
#pragma unroll
            for (int di = 0; di < 4; di++) {
                const float xv = ((const float*)&xq[rl])[di];
                acc[rl][0] = fmaf(xv, wv4[di].x, acc[rl][0]);
                acc[rl][1] = fmaf(xv, wv4[di].y, acc[rl][1]);
                acc[rl][2] = fmaf(xv, wv4[di].z, acc[rl][2]);
                acc[rl][3] = fmaf(xv, wv4[di].w, acc[rl][3]);
            }
    }
#pragma unroll
    for (int rl = 0; rl < RW; rl++) {
        if (rval[rl]) {
            *(float4*)(bp + (size_t)rows[rl] * LSTRIDE + kb) =
                make_float4(acc[rl][0], acc[rl][1], acc[rl][2], acc[rl][3]);
        }
    }
}

__global__ __launch_bounds__(256, 4) void hs_blogits(const float* __restrict__ x,
                                                     const float* __restrict__ Wb,
                                                     const int* __restrict__ bucket,
                                                     const int* __restrict__ cnt,
                                                     float* __restrict__ bws) {
    const int c = blockIdx.x >> 3;  // class
    const int q = blockIdx.x & 7;   // d-chunk
    const int n = cnt[c];
    if (n == 0) return;
    const int lane = threadIdx.x & 63;
    const int wr = threadIdx.x >> 6;  // row-group 0..3
    const float* wq = Wb + (size_t)c * (NHID * TPC) + (size_t)q * CHUNK_D * TPC;
    const float* xb = x + q * CHUNK_D;
    const int* bucket_c = bucket + c * CAP;
    float* bp = bws + (size_t)q * BATCH * LSTRIDE;

    for (int base = 0; base < n; base += 16) {
        int m = n - base;
        if (m > 16) m = 16;
        const int RW = (m + 3) >> 2;
        switch (RW) {  // block-uniform
            case 1: bchunk<1>(xb, wq, bucket_c, base, n, lane, wr, bp); break;
            case 2: bchunk<2>(xb, wq, bucket_c, base, n, lane, wr, bp); break;
            case 3: bchunk<3>(xb, wq, bucket_c, base, n, lane, wr, bp); break;
            default: bchunk<4>(xb, wq, bucket_c, base, n, lane, wr, bp); break;
        }
    }
}

// ---------------------------------------------------------------------------
// Kernel 4: finish. One wave per row: sum partials (16 for top, 8 for
// bottom), softmax, out = p_cls * p_word.
// ---------------------------------------------------------------------------
__global__ __launch_bounds__(256) void hs_finish(const float* __restrict__ tws,
                                                 const float* __restrict__ bws,
                                                 const int* __restrict__ labels,
                                                 const float* __restrict__ b_top,
                                                 const float* __restrict__ b_bot,
                                                 float* __restrict__ out) {
    const int lane = threadIdx.x & 63;
    const int wave = threadIdx.x >> 6;
    const int row = blockIdx.x * 4 + wave;
    const int label = labels[row];
    const int c = label / TPC;
    const int word = label - c * TPC;

    float p[2];
#pragma unroll
    for (int lvl = 0; lvl < 2; lvl++) {
        const int NS = lvl ? TPC : NCLS;
        const int NP = lvl ? NCHUNK : TCH;
        const int pick = lvl ? word : c;
        const float* lws = lvl ? bws : tws;
        const float* bias = lvl ? (b_bot + c * TPC) : b_top;
        float lg[4];
#pragma unroll
        for (int j = 0; j < 4; j++) {
            int k = lane + 64 * j;
            if (k < NS) {
                float v = 0.f;
                for (int pq = 0; pq < NP; pq++)
                    v += lws[((size_t)pq * BATCH + row) * LSTRIDE + k];
                lg[j] = v + bias[k];
            } else {
                lg[j] = -INFINITY;
            }
        }
        float m = fmaxf(fmaxf(lg[0], lg[1]), fmaxf(lg[2], lg[3]));
#pragma unroll
        for (int off = 32; off > 0; off >>= 1) m = fmaxf(m, __shfl_xor(m, off, 64));
        float s = 0.f, pp = 0.f;
#pragma unroll
        for (int j = 0; j < 4; j++) {
            int k = lane + 64 * j;
            float e = (k < NS) ? __expf(lg[j] - m) : 0.f;
            s += e;
            if (k == pick) pp = e;
        }
#pragma unroll
        for (int off = 32; off > 0; off >>= 1) {
            s += __shfl_xor(s, off, 64);
            pp += __shfl_xor(pp, off, 64);
        }
        p[lvl] = pp / s;
    }
    if (lane == 0) out[row] = p[0] * p[1];
}

// ---------------------------------------------------------------------------
extern "C" void kernel_launch(void* const* d_in, const int* in_sizes, int n_in,
                              void* d_out, int out_size, void* d_ws, size_t ws_size,
                              hipStream_t stream) {
    const float* inputs   = (const float*)d_in[0];
    const int*   labels   = (const int*)d_in[1];
    const float* W_top    = (const float*)d_in[2];
    const float* b_top    = (const float*)d_in[3];
    const float* W_bottom = (const float*)d_in[4];
    const float* b_bottom = (const float*)d_in[5];
    float* out = (float*)d_out;

    // ws: bucket[NCLS*CAP] | cnt[NCLS] | tws[16*B*LSTRIDE] | bws[8*B*LSTRIDE]
    int* bucket = (int*)d_ws;
    int* cnt    = bucket + NCLS * CAP;
    float* tws  = (float*)(cnt + NCLS);
    float* bws  = tws + (size_t)TCH * BATCH * LSTRIDE;

    hs_bucket<<<1, 256, 0, stream>>>(labels, bucket, cnt);
    hs_tlogits<<<64 * TCH, 512, 0, stream>>>(inputs, W_top, tws);
    hs_blogits<<<NCLS * NCHUNK, 256, 0, stream>>>(inputs, W_bottom, bucket, cnt, bws);
    hs_finish<<<BATCH / 4, 256, 0, stream>>>(tws, bws, labels, b_top, b_bottom, out);
}

// Round 9
// 458.600 us; speedup vs baseline: 1.0787x; 1.0787x over previous
//
#include <hip/hip_runtime.h>
#include <math.h>

#define TPC 225
#define NCLS 224
#define NHID 1024
#define BATCH 2048
#define CAP 256      // bucket capacity per class (mean ~9.1)
#define LSTRIDE 256  // logits ws row stride (floats)

// tlogits geometry (LDS-staged weights) — proven R8 structure
#define TCH 16       // d-chunks
#define TCH_D 64     // d per chunk
#define TROWS 32     // rows per block (8 waves x 4)
#define TPAD 228     // padded LDS row stride (dwords)

// blogits geometry (LDS-staged weights) — same pattern
#define BCH 16       // d-chunks
#define BCH_D 64     // d per chunk
#define BPAD 228     // padded LDS row stride (dwords, fits 225 + %4==0)

// ---------------------------------------------------------------------------
// Kernel 1: bucket examples by class. Single block, LDS atomics.
// ---------------------------------------------------------------------------
__global__ __launch_bounds__(256) void hs_bucket(const int* __restrict__ labels,
                                                 int* __restrict__ bucket,
                                                 int* __restrict__ cnt) {
    __shared__ int scnt[NCLS];
    const int t = threadIdx.x;
    for (int i = t; i < NCLS; i += 256) scnt[i] = 0;
    __syncthreads();
    for (int b = t; b < BATCH; b += 256) {
        int lab = labels[b];
        int c = lab / TPC;
        int pos = atomicAdd(&scnt[c], 1);
        bucket[c * CAP + pos] = b;
    }
    __syncthreads();
    for (int i = t; i < NCLS; i += 256) cnt[i] = scnt[i];
}

// ---------------------------------------------------------------------------
// Kernel 2: top logits, LDS-staged weights (R8 structure, kept verbatim).
// Grid = 64 row-tiles x 16 chunks; 512 thr = 8 waves x 4 rows.
// ---------------------------------------------------------------------------
__global__ __launch_bounds__(512, 2) void hs_tlogits(const float* __restrict__ x,
                                                     const float* __restrict__ W,
                                                     float* __restrict__ twsP) {
    __shared__ float lw[TCH_D * TPAD];  // 58368 B -> 2 blocks/CU
    const int rb = blockIdx.x >> 4;  // row-tile 0..63
    const int q = blockIdx.x & 15;   // d-chunk 0..15
    const int t = threadIdx.x;
    const int lane = t & 63;
    const int wv = t >> 6;           // wave 0..7

    for (int r = wv; r < TCH_D; r += 8) {
        if (lane < 56) {
            float4 v = *(const float4*)(W + (size_t)(q * TCH_D + r) * NCLS + 4 * lane);
            *(float4*)(&lw[r * TPAD + 4 * lane]) = v;
        }
    }
    __syncthreads();

    int rows[4];
#pragma unroll
    for (int rl = 0; rl < 4; rl++) rows[rl] = rb * TROWS + wv * 4 + rl;
    const float* xp[4];
#pragma unroll
    for (int rl = 0; rl < 4; rl++)
        xp[rl] = x + (size_t)rows[rl] * NHID + q * TCH_D;
    int kcl[4];
#pragma unroll
    for (int j = 0; j < 4; j++) {
        int k = lane + 64 * j;
        kcl[j] = (k < NCLS) ? k : (NCLS - 1);
    }

    float acc[4][4] = {};
    for (int dq = 0; dq < TCH_D / 4; ++dq) {  // 16
        float w[4][4];
#pragma unroll
        for (int di = 0; di < 4; di++)
#pragma unroll
            for (int j = 0; j < 4; j++)
                w[di][j] = lw[(dq * 4 + di) * TPAD + kcl[j]];
        float4 xq[4];
#pragma unroll
        for (int rl = 0; rl < 4; rl++)
            xq[rl] = *(const float4*)(xp[rl] + dq * 4);
#pragma unroll
        for (int rl = 0; rl < 4; rl++)
#pragma unroll
            for (int di = 0; di < 4; di++) {
                float xv = ((const float*)&xq[rl])[di];
#pragma unroll
                for (int j = 0; j < 4; j++)
                    acc[rl][j] = fmaf(xv, w[di][j], acc[rl][j]);
            }
    }

    float* tp = twsP + (size_t)q * BATCH * LSTRIDE;
#pragma unroll
    for (int rl = 0; rl < 4; rl++)
#pragma unroll
        for (int j = 0; j < 4; j++) {
            int k = lane + 64 * j;
            if (k < NCLS) tp[(size_t)rows[rl] * LSTRIDE + k] = acc[rl][j];
        }
}

// ---------------------------------------------------------------------------
// Kernel 3: bottom logits, LDS-staged (same pattern as tlogits — the only
// structure this session proved both correct and beneficial; register-path
// variants are walled at 64 VGPR and spill, R3/R5/R6/R8). Block = one
// (class x 64-d chunk); 8 waves stage the 64x225 W-tile into LDS as dense
// coalesced float4 bursts (HBM latency paid once per tile, not per d-iter),
// then compute rows from conflict-free stride-1 LDS. Row r -> wave (r&7),
// slot (r>>3): load-balanced for mean n~9. (512,2): VGPR cap 256 -> cannot
// spill; LDS 58 KB limits to 2 blocks/CU anyway.
// ---------------------------------------------------------------------------
template <int RW>
__device__ __forceinline__ void bcomp(const float* __restrict__ xb,
                                      const int* __restrict__ bucket_c,
                                      const int base, const int n,
                                      const int lane, const int wv,
                                      const float* __restrict__ lw,
                                      float* __restrict__ bp) {
    int rows[RW], rval[RW];
#pragma unroll
    for (int rl = 0; rl < RW; rl++) {
        int idx = base + wv + 8 * rl;
        rows[rl] = bucket_c[idx < n ? idx : (n - 1)];
        rval[rl] = (idx < n);
    }
    const float* xp[RW];
#pragma unroll
    for (int rl = 0; rl < RW; rl++) xp[rl] = xb + (size_t)rows[rl] * NHID;
    int kcl[4];
#pragma unroll
    for (int j = 0; j < 4; j++) {
        int k = lane + 64 * j;
        kcl[j] = (k < TPC) ? k : (TPC - 1);
    }
    float acc[RW][4];
#pragma unroll
    for (int rl = 0; rl < RW; rl++)
#pragma unroll
        for (int j = 0; j < 4; j++) acc[rl][j] = 0.f;

    for (int dq = 0; dq < BCH_D / 4; ++dq) {  // 16
        float w[4][4];
#pragma unroll
        for (int di = 0; di < 4; di++)
#pragma unroll
            for (int j = 0; j < 4; j++)
                w[di][j] = lw[(dq * 4 + di) * BPAD + kcl[j]];
        float4 xq[RW];
#pragma unroll
        for (int rl = 0; rl < RW; rl++)
            xq[rl] = *(const float4*)(xp[rl] + dq * 4);
#pragma unroll
        for (int rl = 0; rl < RW; rl++)
#pragma unroll
            for (int di = 0; di < 4; di++) {
                float xv = ((const float*)&xq[rl])[di];
#pragma unroll
                for (int j = 0; j < 4; j++)
                    acc[rl][j] = fmaf(xv, w[di][j], acc[rl][j]);
            }
    }
#pragma unroll
    for (int rl = 0; rl < RW; rl++) {
        if (rval[rl]) {
#pragma unroll
            for (int j = 0; j < 4; j++) {
                int k = lane + 64 * j;
                if (k < TPC) bp[(size_t)rows[rl] * LSTRIDE + k] = acc[rl][j];
            }
        }
    }
}

__global__ __launch_bounds__(512, 2) void hs_blogits(const float* __restrict__ x,
                                                     const float* __restrict__ Wb,
                                                     const int* __restrict__ bucket,
                                                     const int* __restrict__ cnt,
                                                     float* __restrict__ bws) {
    __shared__ float lw[BCH_D * BPAD];  // 58368 B
    const int c = blockIdx.x >> 4;  // class
    const int q = blockIdx.x & 15;  // d-chunk
    const int n = cnt[c];
    if (n == 0) return;
    const int t = threadIdx.x;
    const int lane = t & 63;
    const int wv = t >> 6;  // wave 0..7

    // stage: wave wv stages rows wv, wv+8, ... (56 lanes float4 + lane 56
    // scalar for element 224)
    const float* wq = Wb + (size_t)c * (NHID * TPC) + (size_t)q * BCH_D * TPC;
    for (int r = wv; r < BCH_D; r += 8) {
        if (lane < 56) {
            float4 v = *(const float4*)(wq + (size_t)r * TPC + 4 * lane);
            *(float4*)(&lw[r * BPAD + 4 * lane]) = v;
        } else if (lane == 56) {
            lw[r * BPAD + 224] = wq[(size_t)r * TPC + 224];
        }
    }
    __syncthreads();

    const float* xb = x + q * BCH_D;
    const int* bucket_c = bucket + c * CAP;
    float* bp = bws + (size_t)q * BATCH * LSTRIDE;

    for (int base = 0; base < n; base += 32) {
        int m = n - base;
        if (m > 32) m = 32;
        const int RW = (m + 7) >> 3;  // rows per wave, block-uniform
        switch (RW) {
            case 1: bcomp<1>(xb, bucket_c, base, n, lane, wv, lw, bp); break;
            case 2: bcomp<2>(xb, bucket_c, base, n, lane, wv, lw, bp); break;
            case 3: bcomp<3>(xb, bucket_c, base, n, lane, wv, lw, bp); break;
            default: bcomp<4>(xb, bucket_c, base, n, lane, wv, lw, bp); break;
        }
    }
}

// ---------------------------------------------------------------------------
// Kernel 4: finish. One wave per row: sum 16 partials per level, softmax,
// out = p_cls * p_word.
// ---------------------------------------------------------------------------
__global__ __launch_bounds__(256) void hs_finish(const float* __restrict__ tws,
                                                 const float* __restrict__ bws,
                                                 const int* __restrict__ labels,
                                                 const float* __restrict__ b_top,
                                                 const float* __restrict__ b_bot,
                                                 float* __restrict__ out) {
    const int lane = threadIdx.x & 63;
    const int wave = threadIdx.x >> 6;
    const int row = blockIdx.x * 4 + wave;
    const int label = labels[row];
    const int c = label / TPC;
    const int word = label - c * TPC;

    float p[2];
#pragma unroll
    for (int lvl = 0; lvl < 2; lvl++) {
        const int NS = lvl ? TPC : NCLS;
        const int pick = lvl ? word : c;
        const float* lws = lvl ? bws : tws;
        const float* bias = lvl ? (b_bot + c * TPC) : b_top;
        float lg[4];
#pragma unroll
        for (int j = 0; j < 4; j++) {
            int k = lane + 64 * j;
            if (k < NS) {
                float v = 0.f;
                for (int pq = 0; pq < 16; pq++)
                    v += lws[((size_t)pq * BATCH + row) * LSTRIDE + k];
                lg[j] = v + bias[k];
            } else {
                lg[j] = -INFINITY;
            }
        }
        float m = fmaxf(fmaxf(lg[0], lg[1]), fmaxf(lg[2], lg[3]));
#pragma unroll
        for (int off = 32; off > 0; off >>= 1) m = fmaxf(m, __shfl_xor(m, off, 64));
        float s = 0.f, pp = 0.f;
#pragma unroll
        for (int j = 0; j < 4; j++) {
            int k = lane + 64 * j;
            float e = (k < NS) ? __expf(lg[j] - m) : 0.f;
            s += e;
            if (k == pick) pp = e;
        }
#pragma unroll
        for (int off = 32; off > 0; off >>= 1) {
            s += __shfl_xor(s, off, 64);
            pp += __shfl_xor(pp, off, 64);
        }
        p[lvl] = pp / s;
    }
    if (lane == 0) out[row] = p[0] * p[1];
}

// ---------------------------------------------------------------------------
extern "C" void kernel_launch(void* const* d_in, const int* in_sizes, int n_in,
                              void* d_out, int out_size, void* d_ws, size_t ws_size,
                              hipStream_t stream) {
    const float* inputs   = (const float*)d_in[0];
    const int*   labels   = (const int*)d_in[1];
    const float* W_top    = (const float*)d_in[2];
    const float* b_top    = (const float*)d_in[3];
    const float* W_bottom = (const float*)d_in[4];
    const float* b_bottom = (const float*)d_in[5];
    float* out = (float*)d_out;

    // ws: bucket[NCLS*CAP] | cnt[NCLS] | tws[16*B*LSTRIDE] | bws[16*B*LSTRIDE]
    int* bucket = (int*)d_ws;
    int* cnt    = bucket + NCLS * CAP;
    float* tws  = (float*)(cnt + NCLS);
    float* bws  = tws + (size_t)TCH * BATCH * LSTRIDE;

    hs_bucket<<<1, 256, 0, stream>>>(labels, bucket, cnt);
    hs_tlogits<<<64 * TCH, 512, 0, stream>>>(inputs, W_top, tws);
    hs_blogits<<<NCLS * BCH, 512, 0, stream>>>(inputs, W_bottom, bucket, cnt, bws);
    hs_finish<<<BATCH / 4, 256, 0, stream>>>(tws, bws, labels, b_top, b_bottom, out);
}